// Round 1
// baseline (455.165 us; speedup 1.0000x reference)
//
#include <hip/hip_runtime.h>

#define N_NODES 8192
#define IN_F    256
#define OUT_F   128
#define ALPHA_S 0.2f

typedef __attribute__((ext_vector_type(8))) short  short8;
typedef __attribute__((ext_vector_type(4))) short  short4v;
typedef __attribute__((ext_vector_type(4))) float  floatx4;
typedef __attribute__((ext_vector_type(4))) int    intx4;
typedef __attribute__((ext_vector_type(4))) float  fx4;

static __device__ __forceinline__ short f2bf(float f) {
    union { float f; unsigned int i; } u; u.f = f;
    unsigned int r = u.i + 0x7FFFu + ((u.i >> 16) & 1u);  // RNE
    return (short)(r >> 16);
}

// ---------------------------------------------------------------------------
// k_wh: Wh = h @ W via bf16 MFMA -> WhT bf16 [OUT_F][N_NODES].
//       src/dst fp32-exact via q1=W@a1, q2=W@a2 folded into W staging.
// 256 blocks x 512 threads, 32 rows/block. (validated R5/R7; unchanged)
// ---------------------------------------------------------------------------
__global__ __launch_bounds__(512) void k_wh(
    const float* __restrict__ h,    // [N][IN_F] fp32
    const float* __restrict__ W,    // [IN_F][OUT_F] fp32
    const float* __restrict__ a,    // [2*OUT_F] fp32
    short* __restrict__ WhT,        // [OUT_F][N] bf16
    float* __restrict__ src,
    float* __restrict__ dst)
{
    __shared__ short Wt[OUT_F][IN_F + 8];
    __shared__ short htile[32][IN_F + 8];
    __shared__ float q1s[IN_F], q2s[IN_F];
    __shared__ short wh_t[OUT_F][40];

    const int t      = threadIdx.x;
    const int lane   = t & 63;
    const int wave   = t >> 6;
    const int r_base = blockIdx.x * 32;

#pragma unroll
    for (int rep = 0; rep < 4; ++rep) {
        const int idx = rep * 8192 + t * 16;
        const int k   = idx >> 7;
        const int f   = idx & 127;
        fx4 w0 = *(const fx4*)(W + idx);
        fx4 w1 = *(const fx4*)(W + idx + 4);
        fx4 w2 = *(const fx4*)(W + idx + 8);
        fx4 w3 = *(const fx4*)(W + idx + 12);
        fx4 a10 = *(const fx4*)(a + f);
        fx4 a11 = *(const fx4*)(a + f + 4);
        fx4 a12 = *(const fx4*)(a + f + 8);
        fx4 a13 = *(const fx4*)(a + f + 12);
        fx4 a20 = *(const fx4*)(a + OUT_F + f);
        fx4 a21 = *(const fx4*)(a + OUT_F + f + 4);
        fx4 a22 = *(const fx4*)(a + OUT_F + f + 8);
        fx4 a23 = *(const fx4*)(a + OUT_F + f + 12);
        float p1 = 0.f, p2 = 0.f;
#pragma unroll
        for (int e = 0; e < 4; ++e) {
            p1 = fmaf(w0[e], a10[e], p1); p2 = fmaf(w0[e], a20[e], p2);
            p1 = fmaf(w1[e], a11[e], p1); p2 = fmaf(w1[e], a21[e], p2);
            p1 = fmaf(w2[e], a12[e], p1); p2 = fmaf(w2[e], a22[e], p2);
            p1 = fmaf(w3[e], a13[e], p1); p2 = fmaf(w3[e], a23[e], p2);
        }
#pragma unroll
        for (int e = 0; e < 4; ++e) {
            Wt[f + e][k]      = f2bf(w0[e]);
            Wt[f + 4 + e][k]  = f2bf(w1[e]);
            Wt[f + 8 + e][k]  = f2bf(w2[e]);
            Wt[f + 12 + e][k] = f2bf(w3[e]);
        }
#pragma unroll
        for (int m = 1; m < 8; m <<= 1) {
            p1 += __shfl_xor(p1, m, 64);
            p2 += __shfl_xor(p2, m, 64);
        }
        if ((t & 7) == 0) { q1s[k] = p1; q2s[k] = p2; }
    }

    const int r0   = t >> 4;
    const int fgrp = t & 15;
    const int k0   = fgrp * 16;
    fx4 h0, h1, h2, h3;
    {
        const float* hp = h + (size_t)(r_base + r0) * IN_F + k0;
        h0 = *(const fx4*)hp; h1 = *(const fx4*)(hp + 4);
        h2 = *(const fx4*)(hp + 8); h3 = *(const fx4*)(hp + 12);
        short8 b0, b1;
#pragma unroll
        for (int e = 0; e < 4; ++e) {
            b0[e]     = f2bf(h0[e]); b0[4 + e] = f2bf(h1[e]);
            b1[e]     = f2bf(h2[e]); b1[4 + e] = f2bf(h3[e]);
        }
        *(short8*)&htile[r0][k0]     = b0;
        *(short8*)&htile[r0][k0 + 8] = b1;
    }
    __syncthreads();

    {
        float sp = 0.f, dp = 0.f;
#pragma unroll
        for (int e = 0; e < 4; ++e) {
            sp = fmaf(h0[e], q1s[k0 + e], sp);      dp = fmaf(h0[e], q2s[k0 + e], dp);
            sp = fmaf(h1[e], q1s[k0 + 4 + e], sp);  dp = fmaf(h1[e], q2s[k0 + 4 + e], dp);
            sp = fmaf(h2[e], q1s[k0 + 8 + e], sp);  dp = fmaf(h2[e], q2s[k0 + 8 + e], dp);
            sp = fmaf(h3[e], q1s[k0 + 12 + e], sp); dp = fmaf(h3[e], q2s[k0 + 12 + e], dp);
        }
#pragma unroll
        for (int m = 1; m < 16; m <<= 1) {
            sp += __shfl_xor(sp, m, 64);
            dp += __shfl_xor(dp, m, 64);
        }
        if (fgrp == 0) { src[r_base + r0] = sp; dst[r_base + r0] = dp; }
    }

    const int ln15 = lane & 15;
    const int q    = lane >> 4;
    const int f0   = wave * 16;
    floatx4 c0 = {0.f, 0.f, 0.f, 0.f};
    floatx4 c1 = {0.f, 0.f, 0.f, 0.f};
#pragma unroll
    for (int s = 0; s < 8; ++s) {
        short8 bf  = *(const short8*)&Wt[f0 + ln15][s * 32 + q * 8];
        short8 a0f = *(const short8*)&htile[ln15][s * 32 + q * 8];
        short8 a1f = *(const short8*)&htile[16 + ln15][s * 32 + q * 8];
        c0 = __builtin_amdgcn_mfma_f32_16x16x32_bf16(a0f, bf, c0, 0, 0, 0);
        c1 = __builtin_amdgcn_mfma_f32_16x16x32_bf16(a1f, bf, c1, 0, 0, 0);
    }
    {
        short4v p0, p1;
#pragma unroll
        for (int r = 0; r < 4; ++r) { p0[r] = f2bf(c0[r]); p1[r] = f2bf(c1[r]); }
        *(short4v*)&wh_t[f0 + ln15][q * 4]      = p0;
        *(short4v*)&wh_t[f0 + ln15][16 + q * 4] = p1;
    }
    __syncthreads();
    {
        const int f    = t >> 2;
        const int half = t & 3;
        *(short8*)(WhT + (size_t)f * N_NODES + r_base + half * 8) =
            *(const short8*)&wh_t[f][half * 8];
    }
}

// ---------------------------------------------------------------------------
// k_attn: fused full-row attention. BM=32 rows/block, ALL 8192 cols per
// block (jc-split removed), 1024 threads = 16 waves, grid 256 = 1 block/CU,
// zero tail. Same validated single-barrier double-buffer + register-prefetch
// staging structure as before; each wave now owns ONE 16x16 output tile
// (rg = wave>>3 row-group, f0 = (wave&7)*16). Softmax denominator (ones-MFMA
// on waves 0 and 8) is shared through LDS and the ELU epilogue is fused, so
// numer_part/denom_part and k_final are gone (-28 MB write, -16 MB read,
// -1 dispatch).
// ---------------------------------------------------------------------------
#define BM 32
#define BK 128
#define WPAD (BK + 8)
#define NIT (N_NODES / BK)   // 64

__global__ __launch_bounds__(1024, 4) void k_attn(
    const int*   __restrict__ adj,    // [N][N] int32
    const short* __restrict__ WhT,    // [OUT_F][N] bf16
    const float* __restrict__ src,
    const float* __restrict__ dstv,
    float* __restrict__ out)          // [N][OUT_F] fp32
{
    __shared__ short wbuf[2][BM * WPAD];  // 2 x 8.5 KB
    __shared__ float denom_s[BM];

    const int t    = threadIdx.x;
    const int lane = t & 63;
    const int wave = t >> 6;          // 0..15
    const int r0   = blockIdx.x * BM;

    // staging mapping: 32 rows x 128 cols per iter, 4 ints/lane
    const int sm  = t >> 5;           // 0..31
    const int sk0 = (t & 31) * 4;     // 0..124
    const float srow = src[r0 + sm];
    const int*   abase = adj  + (size_t)(r0 + sm) * N_NODES + sk0;
    const float* dbase = dstv + sk0;

    // mfma mapping: one 16x16 tile per wave
    const int ln15 = lane & 15;
    const int q    = lane >> 4;       // 0..3
    const int rg   = wave >> 3;       // row-group 0/1
    const int f0   = (wave & 7) * 16;
    const short* bbase = WhT + (size_t)(f0 + ln15) * N_NODES + q * 8;

    floatx4 acc = {0.f, 0.f, 0.f, 0.f};
    floatx4 dac = {0.f, 0.f, 0.f, 0.f};
    short8 ones;
#pragma unroll
    for (int j = 0; j < 8; ++j) ones[j] = (short)0x3F80;  // bf16 1.0

    // prefetch iter 0
    intx4 m0 = *(const intx4*)abase;
    fx4   d0 = *(const fx4*)dbase;

    for (int it = 0; it < NIT; ++it) {
        const int p = it & 1;
        // exp weights from already-resident regs -> LDS
        short4v wv;
#pragma unroll
        for (int e = 0; e < 4; ++e) {
            float x = srow + d0[e];
            float l = fmaxf(x, ALPHA_S * x);
            wv[e] = (m0[e] > 0) ? f2bf(__expf(l)) : (short)0;
        }
        *(short4v*)&wbuf[p][sm * WPAD + sk0] = wv;
        // issue next iteration's staging loads (hidden behind barrier + MFMA)
        if (it + 1 < NIT) {
            const int o = (it + 1) * BK;
            m0 = *(const intx4*)(abase + o);
            d0 = *(const fx4*)(dbase + o);
        }
        __syncthreads();
        // MFMA on current tile
        const short* ab = &wbuf[p][(rg * 16 + ln15) * WPAD + q * 8];
        const short* bb = bbase + it * BK;
#pragma unroll
        for (int ks = 0; ks < 4; ++ks) {
            short8 afr = *(const short8*)(ab + ks * 32);
            short8 bfr = *(const short8*)(bb + ks * 32);
            acc = __builtin_amdgcn_mfma_f32_16x16x32_bf16(afr, bfr, acc, 0, 0, 0);
            if ((wave & 7) == 0)
                dac = __builtin_amdgcn_mfma_f32_16x16x32_bf16(afr, ones, dac, 0, 0, 0);
        }
    }

    // denominator: waves 0 (rows 0-15) and 8 (rows 16-31); C layout
    // row=(lane>>4)*4+r, col=lane&15 -> ln15==0 lanes hold the rowsums.
    if ((wave & 7) == 0 && ln15 == 0) {
#pragma unroll
        for (int r = 0; r < 4; ++r) denom_s[rg * 16 + q * 4 + r] = dac[r];
    }
    __syncthreads();

    // fused epilogue: divide, ELU, store directly to out
    float* op = out + (size_t)(r0 + rg * 16) * OUT_F + f0 + ln15;
#pragma unroll
    for (int r = 0; r < 4; ++r) {
        float dn = denom_s[rg * 16 + q * 4 + r];
        float v  = acc[r];
        v = (dn != 0.f) ? (v / dn) : 0.f;
        v = v > 0.f ? v : (__expf(v) - 1.f);
        op[(size_t)(q * 4 + r) * OUT_F] = v;
    }
}

// ---------------------------------------------------------------------------
extern "C" void kernel_launch(void* const* d_in, const int* in_sizes, int n_in,
                              void* d_out, int out_size, void* d_ws, size_t ws_size,
                              hipStream_t stream) {
    const float* h   = (const float*)d_in[0];   // fp32 [8192][256]
    const int*   adj = (const int*)d_in[1];     // int32 [8192][8192]
    const float* W   = (const float*)d_in[2];   // fp32 [256][128]
    const float* a   = (const float*)d_in[3];   // fp32 [256]
    float* out = (float*)d_out;                 // fp32 [8192][128]

    char*  ws  = (char*)d_ws;
    short* WhT = (short*)ws;                    // 2 MB
    float* src = (float*)(ws + (2 << 20));      // 32 KB
    float* dst = src + N_NODES;                 // 32 KB

    k_wh  <<<256,  512, 0, stream>>>(h, W, a, WhT, src, dst);
    k_attn<<<256, 1024, 0, stream>>>(adj, WhT, src, dst, out);
}

// Round 2
// 426.329 us; speedup vs baseline: 1.0676x; 1.0676x over previous
//
#include <hip/hip_runtime.h>

#define N_NODES 8192
#define IN_F    256
#define OUT_F   128
#define ALPHA_S 0.2f

typedef __attribute__((ext_vector_type(8))) short  short8;
typedef __attribute__((ext_vector_type(4))) short  short4v;
typedef __attribute__((ext_vector_type(4))) float  floatx4;
typedef __attribute__((ext_vector_type(4))) int    intx4;
typedef __attribute__((ext_vector_type(4))) float  fx4;

static __device__ __forceinline__ short f2bf(float f) {
    union { float f; unsigned int i; } u; u.f = f;
    unsigned int r = u.i + 0x7FFFu + ((u.i >> 16) & 1u);  // RNE
    return (short)(r >> 16);
}
static __device__ __forceinline__ float bf2f(short s) {
    union { float f; unsigned int i; } u;
    u.i = ((unsigned int)(unsigned short)s) << 16;
    return u.f;
}

// ---------------------------------------------------------------------------
// k_wh: Wh = h @ W via bf16 MFMA -> WhT bf16 [OUT_F][N_NODES].
//       src/dst fp32-exact via q1=W@a1, q2=W@a2 folded into W staging.
// 256 blocks x 512 threads, 32 rows/block. (validated; unchanged)
// ---------------------------------------------------------------------------
__global__ __launch_bounds__(512) void k_wh(
    const float* __restrict__ h,    // [N][IN_F] fp32
    const float* __restrict__ W,    // [IN_F][OUT_F] fp32
    const float* __restrict__ a,    // [2*OUT_F] fp32
    short* __restrict__ WhT,        // [OUT_F][N] bf16
    float* __restrict__ src,
    float* __restrict__ dst)
{
    __shared__ short Wt[OUT_F][IN_F + 8];
    __shared__ short htile[32][IN_F + 8];
    __shared__ float q1s[IN_F], q2s[IN_F];
    __shared__ short wh_t[OUT_F][40];

    const int t      = threadIdx.x;
    const int lane   = t & 63;
    const int wave   = t >> 6;
    const int r_base = blockIdx.x * 32;

#pragma unroll
    for (int rep = 0; rep < 4; ++rep) {
        const int idx = rep * 8192 + t * 16;
        const int k   = idx >> 7;
        const int f   = idx & 127;
        fx4 w0 = *(const fx4*)(W + idx);
        fx4 w1 = *(const fx4*)(W + idx + 4);
        fx4 w2 = *(const fx4*)(W + idx + 8);
        fx4 w3 = *(const fx4*)(W + idx + 12);
        fx4 a10 = *(const fx4*)(a + f);
        fx4 a11 = *(const fx4*)(a + f + 4);
        fx4 a12 = *(const fx4*)(a + f + 8);
        fx4 a13 = *(const fx4*)(a + f + 12);
        fx4 a20 = *(const fx4*)(a + OUT_F + f);
        fx4 a21 = *(const fx4*)(a + OUT_F + f + 4);
        fx4 a22 = *(const fx4*)(a + OUT_F + f + 8);
        fx4 a23 = *(const fx4*)(a + OUT_F + f + 12);
        float p1 = 0.f, p2 = 0.f;
#pragma unroll
        for (int e = 0; e < 4; ++e) {
            p1 = fmaf(w0[e], a10[e], p1); p2 = fmaf(w0[e], a20[e], p2);
            p1 = fmaf(w1[e], a11[e], p1); p2 = fmaf(w1[e], a21[e], p2);
            p1 = fmaf(w2[e], a12[e], p1); p2 = fmaf(w2[e], a22[e], p2);
            p1 = fmaf(w3[e], a13[e], p1); p2 = fmaf(w3[e], a23[e], p2);
        }
#pragma unroll
        for (int e = 0; e < 4; ++e) {
            Wt[f + e][k]      = f2bf(w0[e]);
            Wt[f + 4 + e][k]  = f2bf(w1[e]);
            Wt[f + 8 + e][k]  = f2bf(w2[e]);
            Wt[f + 12 + e][k] = f2bf(w3[e]);
        }
#pragma unroll
        for (int m = 1; m < 8; m <<= 1) {
            p1 += __shfl_xor(p1, m, 64);
            p2 += __shfl_xor(p2, m, 64);
        }
        if ((t & 7) == 0) { q1s[k] = p1; q2s[k] = p2; }
    }

    const int r0   = t >> 4;
    const int fgrp = t & 15;
    const int k0   = fgrp * 16;
    fx4 h0, h1, h2, h3;
    {
        const float* hp = h + (size_t)(r_base + r0) * IN_F + k0;
        h0 = *(const fx4*)hp; h1 = *(const fx4*)(hp + 4);
        h2 = *(const fx4*)(hp + 8); h3 = *(const fx4*)(hp + 12);
        short8 b0, b1;
#pragma unroll
        for (int e = 0; e < 4; ++e) {
            b0[e]     = f2bf(h0[e]); b0[4 + e] = f2bf(h1[e]);
            b1[e]     = f2bf(h2[e]); b1[4 + e] = f2bf(h3[e]);
        }
        *(short8*)&htile[r0][k0]     = b0;
        *(short8*)&htile[r0][k0 + 8] = b1;
    }
    __syncthreads();

    {
        float sp = 0.f, dp = 0.f;
#pragma unroll
        for (int e = 0; e < 4; ++e) {
            sp = fmaf(h0[e], q1s[k0 + e], sp);      dp = fmaf(h0[e], q2s[k0 + e], dp);
            sp = fmaf(h1[e], q1s[k0 + 4 + e], sp);  dp = fmaf(h1[e], q2s[k0 + 4 + e], dp);
            sp = fmaf(h2[e], q1s[k0 + 8 + e], sp);  dp = fmaf(h2[e], q2s[k0 + 8 + e], dp);
            sp = fmaf(h3[e], q1s[k0 + 12 + e], sp); dp = fmaf(h3[e], q2s[k0 + 12 + e], dp);
        }
#pragma unroll
        for (int m = 1; m < 16; m <<= 1) {
            sp += __shfl_xor(sp, m, 64);
            dp += __shfl_xor(dp, m, 64);
        }
        if (fgrp == 0) { src[r_base + r0] = sp; dst[r_base + r0] = dp; }
    }

    const int ln15 = lane & 15;
    const int q    = lane >> 4;
    const int f0   = wave * 16;
    floatx4 c0 = {0.f, 0.f, 0.f, 0.f};
    floatx4 c1 = {0.f, 0.f, 0.f, 0.f};
#pragma unroll
    for (int s = 0; s < 8; ++s) {
        short8 bf  = *(const short8*)&Wt[f0 + ln15][s * 32 + q * 8];
        short8 a0f = *(const short8*)&htile[ln15][s * 32 + q * 8];
        short8 a1f = *(const short8*)&htile[16 + ln15][s * 32 + q * 8];
        c0 = __builtin_amdgcn_mfma_f32_16x16x32_bf16(a0f, bf, c0, 0, 0, 0);
        c1 = __builtin_amdgcn_mfma_f32_16x16x32_bf16(a1f, bf, c1, 0, 0, 0);
    }
    {
        short4v p0, p1;
#pragma unroll
        for (int r = 0; r < 4; ++r) { p0[r] = f2bf(c0[r]); p1[r] = f2bf(c1[r]); }
        *(short4v*)&wh_t[f0 + ln15][q * 4]      = p0;
        *(short4v*)&wh_t[f0 + ln15][16 + q * 4] = p1;
    }
    __syncthreads();
    {
        const int f    = t >> 2;
        const int half = t & 3;
        *(short8*)(WhT + (size_t)f * N_NODES + r_base + half * 8) =
            *(const short8*)&wh_t[f][half * 8];
    }
}

// ---------------------------------------------------------------------------
// k_attn v2: fused full-row attention, non-draining pipeline.
//   BM=16 rows/block, 512 threads (8 waves, 1 16x16 tile/wave), grid 512
//   = 2 blocks/CU. BK=256 (32 iters). Depth-2 register prefetch of adj/dst
//   survives the barrier: raw s_barrier with ONLY lgkmcnt(0) drained (ds_write
//   visibility); vmcnt stays counted (compiler-inserted at reg consumption).
//   Denominator = shuffle-reduce of the same bf16 weights (no ones-MFMA
//   straggler wave). ELU epilogue fused.
// Race screen: wave W's lgkmcnt(0) before barrier(i+1) retires its reads of
// buffer (i&1) before any wave passes barrier(i+1); buffer (i&1) is only
// rewritten at iter i+2, after barrier(i+1). Single barrier/iter is sound.
// ---------------------------------------------------------------------------
#define BM 16
#define BK 256
#define WPAD (BK + 8)        // 264 shorts
#define NIT (N_NODES / BK)   // 32

__global__ __launch_bounds__(512, 4) void k_attn(
    const int*   __restrict__ adj,    // [N][N] int32
    const short* __restrict__ WhT,    // [OUT_F][N] bf16
    const float* __restrict__ src,
    const float* __restrict__ dstv,
    float* __restrict__ out)          // [N][OUT_F] fp32
{
    __shared__ short wbuf[2][BM * WPAD];  // 2 x 8.25 KB
    __shared__ float denom_acc[BM];

    const int t    = threadIdx.x;
    const int lane = t & 63;
    const int wave = t >> 6;          // 0..7
    const int r0   = blockIdx.x * BM;

    // staging: 16 rows x 256 cols per iter, 8 ints/lane
    const int sm  = t >> 5;           // 0..15
    const int sk0 = (t & 31) * 8;     // 0..248
    const float srow = src[r0 + sm];
    const int*   abase = adj  + (size_t)(r0 + sm) * N_NODES + sk0;
    const float* dbase = dstv + sk0;

    // mfma mapping: wave owns cols f0..f0+15, all 16 rows
    const int ln15 = lane & 15;
    const int q    = lane >> 4;       // 0..3
    const int f0   = wave * 16;
    const short* bbase = WhT + (size_t)(f0 + ln15) * N_NODES + q * 8;

    if ((t & 31) == 0) denom_acc[sm] = 0.f;  // owner thread inits & accumulates

    floatx4 acc = {0.f, 0.f, 0.f, 0.f};

    // depth-2 register prefetch (named slots, statically indexed)
    intx4 mA0 = *(const intx4*)abase;
    intx4 mA1 = *(const intx4*)(abase + 4);
    fx4   dA0 = *(const fx4*)dbase;
    fx4   dA1 = *(const fx4*)(dbase + 4);
    intx4 mB0 = *(const intx4*)(abase + BK);
    intx4 mB1 = *(const intx4*)(abase + BK + 4);
    fx4   dB0 = *(const fx4*)(dbase + BK);
    fx4   dB1 = *(const fx4*)(dbase + BK + 4);

#define ATTN_STEP(IT, P, M0, M1, D0, D1)                                      \
    {                                                                         \
        short8 wv;                                                            \
        float rsum = 0.f;                                                     \
        _Pragma("unroll") for (int e = 0; e < 4; ++e) {                       \
            float x = srow + D0[e];                                           \
            float l = fmaxf(x, ALPHA_S * x);                                  \
            short b = (M0[e] > 0) ? f2bf(__expf(l)) : (short)0;               \
            wv[e] = b; rsum += bf2f(b);                                       \
        }                                                                     \
        _Pragma("unroll") for (int e = 0; e < 4; ++e) {                       \
            float x = srow + D1[e];                                           \
            float l = fmaxf(x, ALPHA_S * x);                                  \
            short b = (M1[e] > 0) ? f2bf(__expf(l)) : (short)0;               \
            wv[4 + e] = b; rsum += bf2f(b);                                   \
        }                                                                     \
        *(short8*)&wbuf[P][sm * WPAD + sk0] = wv;                             \
        _Pragma("unroll") for (int m = 1; m < 32; m <<= 1)                    \
            rsum += __shfl_xor(rsum, m, 64);                                  \
        if ((t & 31) == 0) denom_acc[sm] += rsum;                             \
        if ((IT) + 2 < NIT) {                                                 \
            const int o = ((IT) + 2) * BK;                                    \
            M0 = *(const intx4*)(abase + o);                                  \
            M1 = *(const intx4*)(abase + o + 4);                              \
            D0 = *(const fx4*)(dbase + o);                                    \
            D1 = *(const fx4*)(dbase + o + 4);                                \
        }                                                                     \
        short8 bfr[8];                                                        \
        const short* bb = bbase + (IT) * BK;                                  \
        _Pragma("unroll") for (int ks = 0; ks < 8; ++ks)                      \
            bfr[ks] = *(const short8*)(bb + ks * 32);                         \
        asm volatile("s_waitcnt lgkmcnt(0)" ::: "memory");                    \
        __builtin_amdgcn_s_barrier();                                         \
        asm volatile("" ::: "memory");                                        \
        const short* ab = &wbuf[P][ln15 * WPAD + q * 8];                      \
        _Pragma("unroll") for (int ks = 0; ks < 8; ++ks) {                    \
            short8 afr = *(const short8*)(ab + ks * 32);                      \
            acc = __builtin_amdgcn_mfma_f32_16x16x32_bf16(afr, bfr[ks], acc,  \
                                                          0, 0, 0);           \
        }                                                                     \
    }

    for (int it = 0; it < NIT; it += 2) {
        ATTN_STEP(it,     0, mA0, mA1, dA0, dA1)
        ATTN_STEP(it + 1, 1, mB0, mB1, dB0, dB1)
    }
#undef ATTN_STEP

    __syncthreads();

    // fused epilogue: divide, ELU, store directly to out
    float* op = out + (size_t)r0 * OUT_F + f0 + ln15;
#pragma unroll
    for (int r = 0; r < 4; ++r) {
        float dn = denom_acc[q * 4 + r];
        float v  = acc[r];
        v = (dn != 0.f) ? (v / dn) : 0.f;
        v = v > 0.f ? v : (__expf(v) - 1.f);
        op[(size_t)(q * 4 + r) * OUT_F] = v;
    }
}

// ---------------------------------------------------------------------------
extern "C" void kernel_launch(void* const* d_in, const int* in_sizes, int n_in,
                              void* d_out, int out_size, void* d_ws, size_t ws_size,
                              hipStream_t stream) {
    const float* h   = (const float*)d_in[0];   // fp32 [8192][256]
    const int*   adj = (const int*)d_in[1];     // int32 [8192][8192]
    const float* W   = (const float*)d_in[2];   // fp32 [256][128]
    const float* a   = (const float*)d_in[3];   // fp32 [256]
    float* out = (float*)d_out;                 // fp32 [8192][128]

    char*  ws  = (char*)d_ws;
    short* WhT = (short*)ws;                    // 2 MB
    float* src = (float*)(ws + (2 << 20));      // 32 KB
    float* dst = src + N_NODES;                 // 32 KB

    k_wh  <<<256, 512, 0, stream>>>(h, W, a, WhT, src, dst);
    k_attn<<<512, 512, 0, stream>>>(adj, WhT, src, dst, out);
}